// Round 16
// baseline (1541.289 us; speedup 1.0000x reference)
//
#include <hip/hip_runtime.h>
#include <hip/hip_bf16.h>

using bf16 = __hip_bfloat16;
typedef __attribute__((ext_vector_type(8))) short short8;
typedef __attribute__((ext_vector_type(4))) float f32x4;
typedef __attribute__((ext_vector_type(4))) int i32x4;

#define NTOK 197
#define MTOK 1576   // 8*197
#define MPATCH 1568 // 8*196

static __device__ __forceinline__ float bf2f(bf16 v){ return __bfloat162float(v); }
static __device__ __forceinline__ bf16 f2bf(float v){ return __float2bfloat16(v); }
static __device__ __forceinline__ float bfs(short s){
  union{ unsigned u; float f; } c; c.u = ((unsigned)(unsigned short)s) << 16; return c.f;
}
static __device__ __forceinline__ unsigned pk2(float a, float b){
  union{ bf16 h[2]; unsigned u; } r; r.h[0]=f2bf(a); r.h[1]=f2bf(b); return r.u;
}

static __device__ __forceinline__ float gelu_tanh(float x){
  float x3 = x*x*x;
  float a = 0.7978845608028654f*(x + 0.044715f*x3);
  float e = __expf(-2.f*fabsf(a));
  float t = (1.f-e)/(1.f+e);
  t = (a >= 0.f) ? t : -t;
  return 0.5f*x*(1.f+t);
}

// direct global->LDS (16B/lane, wave-uniform LDS base + lane*16)
static __device__ __forceinline__ void gload16(const void* g, void* l){
  __builtin_amdgcn_global_load_lds(
      (const __attribute__((address_space(1))) unsigned*)g,
      (__attribute__((address_space(3))) unsigned*)l, 16, 0, 0);
}

template<int N> static __device__ __forceinline__ void wait_vm(){
  if constexpr (N==3)      asm volatile("s_waitcnt vmcnt(3)" ::: "memory");
  else if constexpr (N==5) asm volatile("s_waitcnt vmcnt(5)" ::: "memory");
  else                     asm volatile("s_waitcnt vmcnt(0)" ::: "memory");
}

// ---------------- dequant: 16 elems/iter, one weight group per dispatch ----------------
template<int K>
static __device__ __forceinline__ void dq16(const int* __restrict__ q,
                                            const float* __restrict__ s,
                                            bf16* __restrict__ o, int j){
  constexpr int KP16 = K/16;
  int n = j / KP16;                  // constexpr divisor -> magic multiply
  int k = (j - n*KP16) * 16;
  const i32x4* qp = (const i32x4*)(q + (size_t)n*K + k);
  i32x4 a0 = __builtin_nontemporal_load(qp);
  i32x4 a1 = __builtin_nontemporal_load(qp + 1);
  i32x4 a2 = __builtin_nontemporal_load(qp + 2);
  i32x4 a3 = __builtin_nontemporal_load(qp + 3);
  float sc = s[(size_t)n*(K>>6) + (k>>6)];
  uint4 r0, r1;
  r0.x = pk2(((float)a0.x-7.5f)*sc, ((float)a0.y-7.5f)*sc);
  r0.y = pk2(((float)a0.z-7.5f)*sc, ((float)a0.w-7.5f)*sc);
  r0.z = pk2(((float)a1.x-7.5f)*sc, ((float)a1.y-7.5f)*sc);
  r0.w = pk2(((float)a1.z-7.5f)*sc, ((float)a1.w-7.5f)*sc);
  r1.x = pk2(((float)a2.x-7.5f)*sc, ((float)a2.y-7.5f)*sc);
  r1.y = pk2(((float)a2.z-7.5f)*sc, ((float)a2.w-7.5f)*sc);
  r1.z = pk2(((float)a3.x-7.5f)*sc, ((float)a3.y-7.5f)*sc);
  r1.w = pk2(((float)a3.z-7.5f)*sc, ((float)a3.w-7.5f)*sc);
  bf16* op = o + (size_t)n*K + k;
  *(uint4*)(op)     = r0;
  *(uint4*)(op + 8) = r1;
}

template<int K>
__global__ void dq_k(const int* __restrict__ q, const float* __restrict__ s,
                     bf16* __restrict__ o, int total16){
  #pragma unroll 2
  for (int j = blockIdx.x*256 + threadIdx.x; j < total16; j += gridDim.x*256)
    dq16<K>(q, s, o, j);
}

// ---------------- merged fp32->bf16 converts ----------------
__global__ void cvtall_k(const float* __restrict__ patchw, bf16* __restrict__ patchwb,
                         const float* __restrict__ headw, bf16* __restrict__ headwb,
                         const float* __restrict__ bQ, bf16* __restrict__ bQs,
                         const float* __restrict__ bP, bf16* __restrict__ bPs){
  const int R0 = 768*768/4, R1 = R0 + 512*768/4;
  const int R2 = R1 + 12*2304*64/4, R3 = R2 + 12*768*64/4;
  for (int i = blockIdx.x*256 + threadIdx.x; i < R3; i += gridDim.x*256){
    const float* in; bf16* out; float a; int j;
    if (i < R0){ in=patchw; out=patchwb; a=1.f; j=i; }
    else if (i < R1){ in=headw; out=headwb; a=1.f; j=i-R0; }
    else if (i < R2){ in=bQ; out=bQs; a=0.25f; j=i-R1; }
    else { in=bP; out=bPs; a=0.25f; j=i-R2; }
    float4 v = *(const float4*)(in + (size_t)j*4);
    uint2 r; r.x = pk2(v.x*a, v.y*a); r.y = pk2(v.z*a, v.w*a);
    *(uint2*)(out + (size_t)j*4) = r;
  }
}

// ---------------- LDS-tiled transpose: aQ,aP [12][64][768] f32 -> [12][768][64] bf16 ----------------
__global__ __launch_bounds__(256) void transall_k(const float* __restrict__ aQ, bf16* __restrict__ aQT,
                                                  const float* __restrict__ aP, bf16* __restrict__ aPT){
  __shared__ float tile[64][65];
  const float* in = blockIdx.z ? aP : aQ;
  bf16* out = blockIdx.z ? aPT : aQT;
  const int l = blockIdx.y, c0 = blockIdx.x*64;
  const int t = threadIdx.x;
  const int r = t >> 2, cq = (t & 3) * 16;
  const float* src = in + (size_t)l*64*768 + (size_t)r*768 + c0 + cq;
  #pragma unroll
  for (int j=0;j<4;j++){
    float4 v = *(const float4*)(src + j*4);
    tile[r][cq + j*4 + 0] = v.x; tile[r][cq + j*4 + 1] = v.y;
    tile[r][cq + j*4 + 2] = v.z; tile[r][cq + j*4 + 3] = v.w;
  }
  __syncthreads();
  unsigned w[8];
  #pragma unroll
  for (int j=0;j<8;j++)
    w[j] = pk2(tile[cq + 2*j][r], tile[cq + 2*j + 1][r]);
  bf16* dst = out + ((size_t)l*768 + c0 + r)*64 + cq;
  *(uint4*)(dst)     = *(uint4*)&w[0];
  *(uint4*)(dst + 8) = *(uint4*)&w[4];
}

// ---------------- patchify ----------------
__global__ void patchify_k(const float* __restrict__ img, bf16* __restrict__ p){
  int idx = blockIdx.x*256 + threadIdx.x;
  if (idx >= MPATCH*768) return;
  int col = idx % 768, pr = idx / 768;
  int b = pr / 196, patch = pr % 196;
  int c = col >> 8, rem = col & 255, py = rem >> 4, px = rem & 15;
  int gy = patch / 14, gx = patch % 14;
  float v = img[(((size_t)(b*3 + c))*224 + gy*16 + py)*224 + gx*16 + px];
  p[idx] = f2bf(v);
}

// ---------------- cls row fill ----------------
__global__ void cls_k(const float* __restrict__ cls, float* __restrict__ x){
  int i = blockIdx.x*256 + threadIdx.x;
  if (i >= 8*768) return;
  int b = i / 768, d = i % 768;
  x[(size_t)(b*NTOK)*768 + d] = cls[d];
}

// ---------------- LayerNorm ----------------
__global__ __launch_bounds__(256) void ln_k(const float* __restrict__ x,
                                            const float* __restrict__ g,
                                            const float* __restrict__ b,
                                            bf16* __restrict__ out, int M){
  int row = blockIdx.x*4 + (threadIdx.x >> 6);
  int lane = threadIdx.x & 63;
  if (row >= M) return;
  const float* xr = x + (size_t)row*768;
  float4 v[3]; float s = 0.f;
  #pragma unroll
  for (int j=0;j<3;j++){
    v[j] = *(const float4*)(xr + lane*4 + j*256);
    s += v[j].x + v[j].y + v[j].z + v[j].w;
  }
  #pragma unroll
  for (int o=32;o;o>>=1) s += __shfl_xor(s, o);
  float mean = s * (1.f/768.f);
  float vs = 0.f;
  #pragma unroll
  for (int j=0;j<3;j++){
    float dx=v[j].x-mean, dy=v[j].y-mean, dz=v[j].z-mean, dw=v[j].w-mean;
    vs += dx*dx + dy*dy + dz*dz + dw*dw;
  }
  #pragma unroll
  for (int o=32;o;o>>=1) vs += __shfl_xor(vs, o);
  float rs = rsqrtf(vs*(1.f/768.f) + 1e-6f);
  bf16* orow = out + (size_t)row*768;
  #pragma unroll
  for (int j=0;j<3;j++){
    int d0 = lane*4 + j*256;
    float4 gv = *(const float4*)(g + d0);
    float4 bv = *(const float4*)(b + d0);
    uint2 pk;
    pk.x = pk2((v[j].x-mean)*rs*gv.x + bv.x, (v[j].y-mean)*rs*gv.y + bv.y);
    pk.y = pk2((v[j].z-mean)*rs*gv.z + bv.z, (v[j].w-mean)*rs*gv.w + bv.w);
    *(uint2*)(orow + d0) = pk;
  }
}

// ---------------- MFMA flash attention: 384 blocks x 2 waves (64 q-rows/block) ----------------
__global__ __launch_bounds__(128) void attn_k(const bf16* __restrict__ qkv, bf16* __restrict__ o){
  __shared__ char Kc[2][32*128];
  __shared__ bf16 Vt[2][64][40];
  __shared__ bf16 Pl[2][32][40];

  const int blk = blockIdx.x;
  const int grp = blk & 3, bh = blk >> 2;
  const int b = bh / 12, h = bh % 12;
  const int t = threadIdx.x, wave = t>>6, lane = t&63;
  const int qbase = grp*64 + wave*32;
  const bool alive = qbase < NTOK;
  const bf16* base = qkv + (size_t)b*NTOK*2304 + h*64;

  short8 qf[2][2];
  if (alive){
    #pragma unroll
    for (int qt=0;qt<2;qt++){
      int row = qbase + qt*16 + (lane&15); row = row < NTOK ? row : NTOK-1;
      const bf16* qr = base + (size_t)row*2304 + (lane>>4)*8;
      qf[qt][0] = *(const short8*)(qr);
      qf[qt][1] = *(const short8*)(qr + 32);
    }
  }

  f32x4 Oa[2][4];
  float mrow[2][4], srow[2][4];
  #pragma unroll
  for (int i=0;i<2;i++)
    #pragma unroll
    for (int j=0;j<4;j++){ Oa[i][j] = (f32x4){0.f,0.f,0.f,0.f}; mrow[i][j] = -1e30f; srow[i][j] = 0.f; }

  // staging: 128 threads, 32 kv rows, 32B (16 elems) per thread
  const int sr = t>>2, scq = (t&3)*16;
  auto ldK = [&](int c, uint4& k0, uint4& k1){
    int kv = c*32 + sr; kv = kv < NTOK ? kv : NTOK-1;
    const bf16* kp = base + (size_t)kv*2304 + 768 + scq;
    k0 = *(const uint4*)(kp);
    k1 = *(const uint4*)(kp + 8);
  };
  auto ldV = [&](int c, uint4& v0, uint4& v1){
    int kv = c*32 + sr;
    v0 = (uint4){0,0,0,0}; v1 = (uint4){0,0,0,0};
    if (kv < NTOK){
      const bf16* vp = base + (size_t)kv*2304 + 1536 + scq;
      v0 = *(const uint4*)(vp);
      v1 = *(const uint4*)(vp + 8);
    }
  };
  auto wrK = [&](int buf, uint4 k0, uint4 k1){
    int swz = (sr&7)<<4, cb = scq*2;
    *(uint4*)(Kc[buf] + sr*128 + (cb ^ swz))        = k0;
    *(uint4*)(Kc[buf] + sr*128 + ((cb+16) ^ swz))   = k1;
  };
  auto wrV = [&](int buf, uint4 v0, uint4 v1){
    union{ uint4 u; short s[8]; } w0, w1; w0.u = v0; w1.u = v1;
    #pragma unroll
    for (int j=0;j<8;j++){
      *(short*)&Vt[buf][scq+j][sr]   = w0.s[j];
      *(short*)&Vt[buf][scq+8+j][sr] = w1.s[j];
    }
  };

  { uint4 k0,k1,v0,v1; ldK(0,k0,k1); ldV(0,v0,v1); wrK(0,k0,k1); wrV(0,v0,v1); }
  __syncthreads();

  for (int c=0;c<7;c++){
    const int buf = c & 1;
    uint4 kn0,kn1,vn0,vn1; const bool pf = (c < 6);
    if (pf){ ldK(c+1,kn0,kn1); ldV(c+1,vn0,vn1); }

    if (alive){
      f32x4 S[2][2];
      #pragma unroll
      for (int i=0;i<2;i++)
        #pragma unroll
        for (int j=0;j<2;j++) S[i][j] = (f32x4){0.f,0.f,0.f,0.f};
      #pragma unroll
      for (int kt=0;kt<2;kt++){
        int rk = kt*16 + (lane&15);
        const char* kb = Kc[buf] + rk*128;
        int swz = (rk&7)<<4;
        short8 b0 = *(const short8*)(kb + (((lane>>4)*16) ^ swz));
        short8 b1 = *(const short8*)(kb + ((64 + (lane>>4)*16) ^ swz));
        #pragma unroll
        for (int qt=0;qt<2;qt++){
          S[qt][kt] = __builtin_amdgcn_mfma_f32_16x16x32_bf16(qf[qt][0], b0, S[qt][kt],0,0,0);
          S[qt][kt] = __builtin_amdgcn_mfma_f32_16x16x32_bf16(qf[qt][1], b1, S[qt][kt],0,0,0);
        }
      }

      #pragma unroll
      for (int qt=0;qt<2;qt++){
        #pragma unroll
        for (int r=0;r<4;r++){
          float s0 = S[qt][0][r]*0.125f, s1 = S[qt][1][r]*0.125f;
          if (c == 6){
            if (192 + (lane&15) >= NTOK) s0 = -1e30f;
            s1 = -1e30f;
          }
          float mx = fmaxf(s0, s1);
          mx = fmaxf(mx, __shfl_xor(mx,1));
          mx = fmaxf(mx, __shfl_xor(mx,2));
          mx = fmaxf(mx, __shfl_xor(mx,4));
          mx = fmaxf(mx, __shfl_xor(mx,8));
          float mo = mrow[qt][r];
          float mn = fmaxf(mo, mx);
          float scl = __expf(mo - mn);
          mrow[qt][r] = mn;
          float p0 = __expf(s0 - mn), p1 = __expf(s1 - mn);
          srow[qt][r] = srow[qt][r]*scl + p0 + p1;
          #pragma unroll
          for (int dt=0;dt<4;dt++) Oa[qt][dt][r] *= scl;
          int pr = qt*16 + (lane>>4)*4 + r;
          Pl[wave][pr][lane&15]      = f2bf(p0);
          Pl[wave][pr][16+(lane&15)] = f2bf(p1);
        }
      }

      short8 vb[4];
      #pragma unroll
      for (int dt=0;dt<4;dt++)
        vb[dt] = *(const short8*)(&Vt[buf][dt*16+(lane&15)][(lane>>4)*8]);
      #pragma unroll
      for (int qt=0;qt<2;qt++){
        short8 pa = *(const short8*)(&Pl[wave][qt*16+(lane&15)][(lane>>4)*8]);
        #pragma unroll
        for (int dt=0;dt<4;dt++)
          Oa[qt][dt] = __builtin_amdgcn_mfma_f32_16x16x32_bf16(pa, vb[dt], Oa[qt][dt],0,0,0);
      }
    }

    if (pf){ wrK(buf^1, kn0, kn1); wrV(buf^1, vn0, vn1); }
    __syncthreads();
  }

  if (alive){
    #pragma unroll
    for (int qt=0;qt<2;qt++)
      #pragma unroll
      for (int r=0;r<4;r++){
        float s = srow[qt][r];
        s += __shfl_xor(s,1); s += __shfl_xor(s,2);
        s += __shfl_xor(s,4); s += __shfl_xor(s,8);
        srow[qt][r] = 1.f/s;
      }
    #pragma unroll
    for (int qt=0;qt<2;qt++){
      #pragma unroll
      for (int r=0;r<4;r++){
        int tok = qbase + qt*16 + (lane>>4)*4 + r;
        if (tok < NTOK){
          bf16* orow = o + ((size_t)(b*NTOK+tok))*768 + h*64 + (lane&15);
          float inv = srow[qt][r];
          #pragma unroll
          for (int dt=0;dt<4;dt++) orow[dt*16] = f2bf(Oa[qt][dt][r]*inv);
        }
      }
    }
  }
}

// ---------------- fused tail: mean-pool + LN + head matmul + relu (1 block/batch) ----------------
__global__ __launch_bounds__(256) void tail_k(const float* __restrict__ x,
                                              const float* __restrict__ fcng,
                                              const float* __restrict__ fcnb,
                                              const bf16* __restrict__ headwb,
                                              const float* __restrict__ headb,
                                              float* __restrict__ out){
  __shared__ float pooled[768];
  __shared__ bf16 nrm[768];
  __shared__ float red[8];
  const int b = blockIdx.x, t = threadIdx.x;
  const int wave = t>>6, lane = t&63;
  float acc[3];
  #pragma unroll
  for (int j=0;j<3;j++){
    int d = t + j*256;
    const float* col = x + (size_t)(b*NTOK)*768 + d;
    float s0=0.f,s1=0.f,s2=0.f,s3=0.f;
    for (int i=1;i<=196;i+=4){
      s0 += col[(size_t)i*768];     s1 += col[(size_t)(i+1)*768];
      s2 += col[(size_t)(i+2)*768]; s3 += col[(size_t)(i+3)*768];
    }
    acc[j] = (s0+s1+s2+s3) * (1.f/196.f);
    pooled[d] = acc[j];
  }
  float ls=0.f, lq=0.f;
  #pragma unroll
  for (int j=0;j<3;j++){ ls += acc[j]; lq += acc[j]*acc[j]; }
  #pragma unroll
  for (int o=32;o;o>>=1){ ls += __shfl_xor(ls,o); lq += __shfl_xor(lq,o); }
  if (lane==0){ red[wave] = ls; red[4+wave] = lq; }
  __syncthreads();
  float ts = red[0]+red[1]+red[2]+red[3];
  float tq = red[4]+red[5]+red[6]+red[7];
  float mean = ts * (1.f/768.f);
  float var  = tq * (1.f/768.f) - mean*mean;
  float rs = rsqrtf(var + 1e-6f);
  #pragma unroll
  for (int j=0;j<3;j++){
    int d = t + j*256;
    nrm[d] = f2bf((pooled[d]-mean)*rs*fcng[d] + fcnb[d]);
  }
  __syncthreads();
  #pragma unroll
  for (int j=0;j<2;j++){
    int oo = t + j*256;
    const bf16* wrow = headwb + (size_t)oo*768;
    float a = 0.f;
    for (int k=0;k<768;k+=8){
      short8 wv = *(const short8*)(wrow + k);
      short8 nv = *(const short8*)(&nrm[k]);
      #pragma unroll
      for (int e=0;e<8;e++) a += bfs(wv[e]) * bfs(nv[e]);
    }
    out[(size_t)b*512 + oo] = fmaxf(a + headb[oo], 0.f);
  }
}

// ==================================================================
// Unified bf16 GEMM via global_load_lds (round-9 proven config, FROZEN)
// ==================================================================
template<int BM, int BN, int OUTMODE, int ACT, int FOLD>
__global__ __launch_bounds__(256) void gemm_k(
    const bf16* __restrict__ A, const bf16* __restrict__ W,
    const float* __restrict__ bias, const float* __restrict__ gvec,
    void* __restrict__ Cout,
    int M, int N, int Kst, int kiters, size_t kslab)
{
  constexpr int WCM = BM/2;
  constexpr int WCN = BN/2;
  constexpr int FM  = WCM/16;
  constexpr int FN  = WCN/16;
  constexpr int NW  = BN/32;
  constexpr int LCNT = 1 + NW;

  __shared__ char As[2][BM*128];
  __shared__ char Bs[2][BN*128];

  int mt, nt;
  {
    int gmy = gridDim.y;
    int nwg = gridDim.x * gmy;
    int bid = blockIdx.y * gridDim.x + blockIdx.x;
    int q8 = nwg >> 3, r8 = nwg & 7, xcd = bid & 7, idx = bid >> 3;
    int swz = (xcd < r8 ? xcd*(q8+1) : r8*(q8+1) + (xcd-r8)*q8) + idx;
    nt = swz / gmy; mt = swz - nt*gmy;
  }
  if (FOLD){
    A += (size_t)blockIdx.z * (size_t)M * 64;
    W += (size_t)blockIdx.z * (size_t)N * 64;
  }
  const int kz = FOLD ? 0 : blockIdx.z;
  const int k0 = kz * kiters;
  const int t = threadIdx.x, wave = t>>6, lane = t&63;
  const int wr = wave>>1, wc = wave&1;
  const int KT = kiters;

  const int srow = t >> 3;
  const int swzc = ((t&7)<<4) ^ ((srow&7)<<4);

  f32x4 acc[FM][FN];
  #pragma unroll
  for (int i=0;i<FM;i++)
    #pragma unroll
    for (int j=0;j<FN;j++) acc[i][j] = (f32x4){0.f,0.f,0.f,0.f};

  auto STAGE = [&](int it, int buf){
    {
      int gm = mt*BM + srow; gm = gm < M ? gm : M-1;
      gload16((const char*)A + (size_t)gm*Kst*2 + (size_t)(k0+it)*128 + swzc,
              As[buf] + wave*1024);
    }
    #pragma unroll
    for (int c=0;c<NW;c++){
      int gn = nt*BN + 32*c + srow;
      gload16((const char*)W + (size_t)gn*Kst*2 + (size_t)(k0+it)*128 + swzc,
              Bs[buf] + c*4096 + wave*1024);
    }
  };

  const int lrow = lane & 15;
  const int lkb  = (lane >> 4) * 16;
  auto computeTile = [&](int buf){
    __builtin_amdgcn_s_setprio(1);
    #pragma unroll
    for (int kk=0; kk<2; kk++){
      short8 af[FM]; short8 bw[FN];
      #pragma unroll
      for (int f=0; f<FM; f++){
        int ra = wr*WCM + f*16 + lrow;
        af[f] = *(const short8*)(As[buf] + ra*128 + ((kk*64 + lkb) ^ ((ra&7)<<4)));
      }
      #pragma unroll
      for (int f=0; f<FN; f++){
        int rb = wc*WCN + f*16 + lrow;
        bw[f] = *(const short8*)(Bs[buf] + rb*128 + ((kk*64 + lkb) ^ ((rb&7)<<4)));
      }
      #pragma unroll
      for (int i=0;i<FM;i++)
        #pragma unroll
        for (int j=0;j<FN;j++)
          acc[i][j] = __builtin_amdgcn_mfma_f32_16x16x32_bf16(af[i], bw[j], acc[i][j], 0, 0, 0);
    }
    __builtin_amdgcn_s_setprio(0);
  };

  STAGE(0, 0);
  if (KT > 1) STAGE(1, 1);

  for (int it = 0; it < KT; ++it){
    if (it == KT-1) wait_vm<0>(); else wait_vm<LCNT>();
    __builtin_amdgcn_s_barrier();
    computeTile(it & 1);
    asm volatile("s_waitcnt lgkmcnt(0)" ::: "memory");
    __builtin_amdgcn_s_barrier();
    if (it+2 < KT) STAGE(it+2, it & 1);
  }

  const int erow = (lane >> 4) * 4, ecol = lane & 15;
  #pragma unroll
  for (int i=0;i<FM;i++){
    #pragma unroll
    for (int j=0;j<FN;j++){
      int n = nt*BN + wc*WCN + j*16 + ecol;
      float bv = (bias != nullptr) ? bias[n] : 0.f;
      float gv = (OUTMODE==2) ? gvec[n] : 0.f;
      #pragma unroll
      for (int q=0; q<4; q++){
        int m = mt*BM + wr*WCM + i*16 + erow + q;
        if (m < M){
          float v = acc[i][j][q] + bv;
          if (ACT == 1) v = gelu_tanh(v);
          if (ACT == 2) v = fmaxf(v, 0.f);
          size_t off = (size_t)m*N + n;
          if (OUTMODE == 0)      ((float*)Cout)[(size_t)kz*kslab + off] = v;
          else if (OUTMODE == 1) ((bf16*)Cout)[off] = f2bf(v);
          else if (OUTMODE == 2) ((float*)Cout)[off] += gv * v;
          else if (OUTMODE == 4){
            int bb = m / 196, rr = m - bb*196;
            ((float*)Cout)[((size_t)(bb*NTOK + rr + 1))*768 + n] = v;
          }
          else {
            bf16* C = (bf16*)Cout + (FOLD ? (size_t)blockIdx.z*(size_t)M*N : (size_t)0);
            C[off] = f2bf(bf2f(C[off]) + v);
          }
        }
      }
    }
  }
}

// ===================================================================
extern "C" void kernel_launch(void* const* d_in, const int* in_sizes, int n_in,
                              void* d_out, int out_size, void* d_ws, size_t ws_size,
                              hipStream_t stream){
  (void)in_sizes; (void)n_in; (void)out_size; (void)ws_size;
  const float* img    = (const float*)d_in[0];
  const float* patchw = (const float*)d_in[1];
  const float* patchb = (const float*)d_in[2];
  const float* cls    = (const float*)d_in[3];
  const float* ln1g   = (const float*)d_in[4];
  const float* ln1b   = (const float*)d_in[5];
  const float* ln2g   = (const float*)d_in[6];
  const float* ln2b   = (const float*)d_in[7];
  const float* g1     = (const float*)d_in[8];
  const float* g2     = (const float*)d_in[9];
  const int*   qkvq   = (const int*)d_in[10];
  const float* qkvs   = (const float*)d_in[11];
  const float* qkvb   = (const float*)d_in[12];
  const float* aQ     = (const float*)d_in[13];
  const float* bQ     = (const float*)d_in[14];
  const int*   projq  = (const int*)d_in[15];
  const float* projs  = (const float*)d_in[16];
  const float* projb  = (const float*)d_in[17];
  const float* aP     = (const float*)d_in[18];
  const float* bP     = (const float*)d_in[19];
  const int*   fc1q   = (const int*)d_in[20];
  const float* fc1s   = (const float*)d_in[21];
  const float* fc1b   = (const float*)d_in[22];
  const int*   fc2q   = (const int*)d_in[23];
  const float* fc2s   = (const float*)d_in[24];
  const float* fc2b   = (const float*)d_in[25];
  const float* fcn_g  = (const float*)d_in[26];
  const float* fcn_b  = (const float*)d_in[27];
  const float* headw  = (const float*)d_in[28];
  const float* headb  = (const float*)d_in[29];
  float* out = (float*)d_out;

  char* wp = (char*)d_ws;
  auto alloc = [&](size_t bytes)->char* {
    char* r = wp; wp += (bytes + 255) & ~(size_t)255; return r;
  };
  float* x      = (float*)alloc((size_t)MTOK*768*4);
  bf16*  qkvo   = (bf16*) alloc((size_t)MTOK*2304*2);
  bf16*  h      = (bf16*) alloc((size_t)MTOK*768*2);
  bf16*  h1     = (bf16*) alloc((size_t)MTOK*3072*2);
  bf16*  ob     = (bf16*) alloc((size_t)MTOK*768*2);
  bf16*  p      = (bf16*) alloc((size_t)MPATCH*768*2);
  bf16* wqb = (bf16*)alloc((size_t)12*2304*768*2);
  bf16* wpb = (bf16*)alloc((size_t)12*768*768*2);
  bf16* w1b = (bf16*)alloc((size_t)12*3072*768*2);
  bf16* w2b = (bf16*)alloc((size_t)12*768*3072*2);
  bf16* patchwb = (bf16*)alloc((size_t)768*768*2);
  bf16* headwb  = (bf16*)alloc((size_t)512*768*2);
  bf16* bQs = (bf16*)alloc((size_t)12*2304*64*2);
  bf16* bPs = (bf16*)alloc((size_t)12*768*64*2);
  bf16* aQT = (bf16*)alloc((size_t)12*768*64*2);
  bf16* aPT = (bf16*)alloc((size_t)12*768*64*2);

  const int GM32 = (MTOK + 31) / 32;   // 50

  // ---- one-time weight prep ----
  dq_k<768><<<2048, 256, 0, stream>>>(qkvq, qkvs, wqb, 12*2304*768/16);
  dq_k<768><<<2048, 256, 0, stream>>>(projq, projs, wpb, 12*768*768/16);
  dq_k<768><<<2048, 256, 0, stream>>>(fc1q, fc1s, w1b, 6*3072*768/16);
  dq_k<768><<<2048, 256, 0, stream>>>(fc1q + (size_t)6*3072*768, fc1s + (size_t)6*3072*12,
                                      w1b + (size_t)6*3072*768, 6*3072*768/16);
  dq_k<3072><<<2048, 256, 0, stream>>>(fc2q, fc2s, w2b, 6*768*3072/16);
  dq_k<3072><<<2048, 256, 0, stream>>>(fc2q + (size_t)6*768*3072, fc2s + (size_t)6*768*48,
                                       w2b + (size_t)6*768*3072, 6*768*3072/16);
  cvtall_k<<<1024, 256, 0, stream>>>(patchw, patchwb, headw, headwb, bQ, bQs, bP, bPs);
  transall_k<<<dim3(12, 12, 2), 256, 0, stream>>>(aQ, aQT, aP, aPT);
  gemm_k<32,64,3,0,1><<<dim3(768/64, 2304/32, 12), 256, 0, stream>>>(
      bQs, aQT, nullptr, nullptr, wqb, 2304, 768, 64, 1, 0);
  gemm_k<32,64,3,0,1><<<dim3(768/64, 768/32, 12), 256, 0, stream>>>(
      bPs, aPT, nullptr, nullptr, wpb, 768, 768, 64, 1, 0);

  patchify_k<<<(MPATCH*768 + 255)/256, 256, 0, stream>>>(img, p);
  gemm_k<32,64,4,0,0><<<dim3(768/64, MPATCH/32, 1), 256, 0, stream>>>(
      p, patchwb, patchb, nullptr, x, MPATCH, 768, 768, 12, 0);
  cls_k<<<(8*768 + 255)/256, 256, 0, stream>>>(cls, x);

  for (int l=0; l<12; l++){
    const bf16* wq_l = wqb + (size_t)l*2304*768;
    const bf16* wp_l = wpb + (size_t)l*768*768;
    const bf16* w1_l = w1b + (size_t)l*3072*768;
    const bf16* w2_l = w2b + (size_t)l*768*3072;

    ln_k<<<(MTOK+3)/4, 256, 0, stream>>>(x, ln1g + l*768, ln1b + l*768, h, MTOK);
    gemm_k<32,128,1,0,0><<<dim3(2304/128, GM32, 1), 256, 0, stream>>>(
        h, wq_l, qkvb + (size_t)l*2304, nullptr, qkvo, MTOK, 2304, 768, 12, 0);
    attn_k<<<384, 128, 0, stream>>>(qkvo, ob);
    gemm_k<32,64,2,0,0><<<dim3(768/64, GM32, 1), 256, 0, stream>>>(
        ob, wp_l, projb + (size_t)l*768, g1 + l*768, x, MTOK, 768, 768, 12, 0);

    ln_k<<<(MTOK+3)/4, 256, 0, stream>>>(x, ln2g + l*768, ln2b + l*768, h, MTOK);
    gemm_k<32,128,1,1,0><<<dim3(3072/128, GM32, 1), 256, 0, stream>>>(
        h, w1_l, fc1b + (size_t)l*3072, nullptr, h1, MTOK, 3072, 768, 12, 0);
    gemm_k<32,64,2,0,0><<<dim3(768/64, GM32, 1), 256, 0, stream>>>(
        h1, w2_l, fc2b + (size_t)l*768, g2 + l*768, x, MTOK, 768, 3072, 48, 0);
  }

  tail_k<<<8, 256, 0, stream>>>(x, fcn_g, fcn_b, headwb, headb, out);
}

// Round 17
// 1464.978 us; speedup vs baseline: 1.0521x; 1.0521x over previous
//
#include <hip/hip_runtime.h>
#include <hip/hip_bf16.h>

using bf16 = __hip_bfloat16;
typedef __attribute__((ext_vector_type(8))) short short8;
typedef __attribute__((ext_vector_type(4))) float f32x4;
typedef __attribute__((ext_vector_type(4))) int i32x4;

#define NTOK 197
#define MTOK 1576   // 8*197
#define MPATCH 1568 // 8*196

static __device__ __forceinline__ float bf2f(bf16 v){ return __bfloat162float(v); }
static __device__ __forceinline__ bf16 f2bf(float v){ return __float2bfloat16(v); }
static __device__ __forceinline__ unsigned pk2(float a, float b){
  union{ bf16 h[2]; unsigned u; } r; r.h[0]=f2bf(a); r.h[1]=f2bf(b); return r.u;
}

static __device__ __forceinline__ float gelu_tanh(float x){
  float x3 = x*x*x;
  float a = 0.7978845608028654f*(x + 0.044715f*x3);
  float e = __expf(-2.f*fabsf(a));
  float t = (1.f-e)/(1.f+e);
  t = (a >= 0.f) ? t : -t;
  return 0.5f*x*(1.f+t);
}

// direct global->LDS (16B/lane, wave-uniform LDS base + lane*16)
static __device__ __forceinline__ void gload16(const void* g, void* l){
  __builtin_amdgcn_global_load_lds(
      (const __attribute__((address_space(1))) unsigned*)g,
      (__attribute__((address_space(3))) unsigned*)l, 16, 0, 0);
}

template<int N> static __device__ __forceinline__ void wait_vm(){
  if constexpr (N==3)      asm volatile("s_waitcnt vmcnt(3)" ::: "memory");
  else if constexpr (N==5) asm volatile("s_waitcnt vmcnt(5)" ::: "memory");
  else                     asm volatile("s_waitcnt vmcnt(0)" ::: "memory");
}

// ---------------- dequant: 16 elems/iter, one weight group per dispatch ----------------
template<int K>
static __device__ __forceinline__ void dq16(const int* __restrict__ q,
                                            const float* __restrict__ s,
                                            bf16* __restrict__ o, int j){
  constexpr int KP16 = K/16;
  int n = j / KP16;                  // constexpr divisor -> magic multiply
  int k = (j - n*KP16) * 16;
  const i32x4* qp = (const i32x4*)(q + (size_t)n*K + k);
  i32x4 a0 = __builtin_nontemporal_load(qp);
  i32x4 a1 = __builtin_nontemporal_load(qp + 1);
  i32x4 a2 = __builtin_nontemporal_load(qp + 2);
  i32x4 a3 = __builtin_nontemporal_load(qp + 3);
  float sc = s[(size_t)n*(K>>6) + (k>>6)];
  uint4 r0, r1;
  r0.x = pk2(((float)a0.x-7.5f)*sc, ((float)a0.y-7.5f)*sc);
  r0.y = pk2(((float)a0.z-7.5f)*sc, ((float)a0.w-7.5f)*sc);
  r0.z = pk2(((float)a1.x-7.5f)*sc, ((float)a1.y-7.5f)*sc);
  r0.w = pk2(((float)a1.z-7.5f)*sc, ((float)a1.w-7.5f)*sc);
  r1.x = pk2(((float)a2.x-7.5f)*sc, ((float)a2.y-7.5f)*sc);
  r1.y = pk2(((float)a2.z-7.5f)*sc, ((float)a2.w-7.5f)*sc);
  r1.z = pk2(((float)a3.x-7.5f)*sc, ((float)a3.y-7.5f)*sc);
  r1.w = pk2(((float)a3.z-7.5f)*sc, ((float)a3.w-7.5f)*sc);
  bf16* op = o + (size_t)n*K + k;
  *(uint4*)(op)     = r0;
  *(uint4*)(op + 8) = r1;
}

template<int K>
__global__ void dq_k(const int* __restrict__ q, const float* __restrict__ s,
                     bf16* __restrict__ o, int total16){
  #pragma unroll 2
  for (int j = blockIdx.x*256 + threadIdx.x; j < total16; j += gridDim.x*256)
    dq16<K>(q, s, o, j);
}

// ---------------- merged fp32->bf16 converts (patchw, headw, 0.25*bQ, 0.25*bP) ----------------
__global__ void cvtall_k(const float* __restrict__ patchw, bf16* __restrict__ patchwb,
                         const float* __restrict__ headw, bf16* __restrict__ headwb,
                         const float* __restrict__ bQ, bf16* __restrict__ bQs,
                         const float* __restrict__ bP, bf16* __restrict__ bPs){
  const int R0 = 768*768/4, R1 = R0 + 512*768/4;
  const int R2 = R1 + 12*2304*64/4, R3 = R2 + 12*768*64/4;
  for (int i = blockIdx.x*256 + threadIdx.x; i < R3; i += gridDim.x*256){
    const float* in; bf16* out; float a; int j;
    if (i < R0){ in=patchw; out=patchwb; a=1.f; j=i; }
    else if (i < R1){ in=headw; out=headwb; a=1.f; j=i-R0; }
    else if (i < R2){ in=bQ; out=bQs; a=0.25f; j=i-R1; }
    else { in=bP; out=bPs; a=0.25f; j=i-R2; }
    float4 v = *(const float4*)(in + (size_t)j*4);
    uint2 r; r.x = pk2(v.x*a, v.y*a); r.y = pk2(v.z*a, v.w*a);
    *(uint2*)(out + (size_t)j*4) = r;
  }
}

// ---------------- LDS-tiled transpose: aQ,aP [12][64][768] f32 -> [12][768][64] bf16 ----------------
__global__ __launch_bounds__(256) void transall_k(const float* __restrict__ aQ, bf16* __restrict__ aQT,
                                                  const float* __restrict__ aP, bf16* __restrict__ aPT){
  __shared__ float tile[64][65];
  const float* in = blockIdx.z ? aP : aQ;
  bf16* out = blockIdx.z ? aPT : aQT;
  const int l = blockIdx.y, c0 = blockIdx.x*64;
  const int t = threadIdx.x;
  const int r = t >> 2, cq = (t & 3) * 16;
  const float* src = in + (size_t)l*64*768 + (size_t)r*768 + c0 + cq;
  #pragma unroll
  for (int j=0;j<4;j++){
    float4 v = *(const float4*)(src + j*4);
    tile[r][cq + j*4 + 0] = v.x; tile[r][cq + j*4 + 1] = v.y;
    tile[r][cq + j*4 + 2] = v.z; tile[r][cq + j*4 + 3] = v.w;
  }
  __syncthreads();
  unsigned w[8];
  #pragma unroll
  for (int j=0;j<8;j++)
    w[j] = pk2(tile[cq + 2*j][r], tile[cq + 2*j + 1][r]);
  bf16* dst = out + ((size_t)l*768 + c0 + r)*64 + cq;
  *(uint4*)(dst)     = *(uint4*)&w[0];
  *(uint4*)(dst + 8) = *(uint4*)&w[4];
}

// ---------------- patchify ----------------
__global__ void patchify_k(const float* __restrict__ img, bf16* __restrict__ p){
  int idx = blockIdx.x*256 + threadIdx.x;
  if (idx >= MPATCH*768) return;
  int col = idx % 768, pr = idx / 768;
  int b = pr / 196, patch = pr % 196;
  int c = col >> 8, rem = col & 255, py = rem >> 4, px = rem & 15;
  int gy = patch / 14, gx = patch % 14;
  float v = img[(((size_t)(b*3 + c))*224 + gy*16 + py)*224 + gx*16 + px];
  p[idx] = f2bf(v);
}

// ---------------- cls row fill ----------------
__global__ void cls_k(const float* __restrict__ cls, float* __restrict__ x){
  int i = blockIdx.x*256 + threadIdx.x;
  if (i >= 8*768) return;
  int b = i / 768, d = i % 768;
  x[(size_t)(b*NTOK)*768 + d] = cls[d];
}

// ---------------- LayerNorm ----------------
__global__ __launch_bounds__(256) void ln_k(const float* __restrict__ x,
                                            const float* __restrict__ g,
                                            const float* __restrict__ b,
                                            bf16* __restrict__ out, int M){
  int row = blockIdx.x*4 + (threadIdx.x >> 6);
  int lane = threadIdx.x & 63;
  if (row >= M) return;
  const float* xr = x + (size_t)row*768;
  float4 v[3]; float s = 0.f;
  #pragma unroll
  for (int j=0;j<3;j++){
    v[j] = *(const float4*)(xr + lane*4 + j*256);
    s += v[j].x + v[j].y + v[j].z + v[j].w;
  }
  #pragma unroll
  for (int o=32;o;o>>=1) s += __shfl_xor(s, o);
  float mean = s * (1.f/768.f);
  float vs = 0.f;
  #pragma unroll
  for (int j=0;j<3;j++){
    float dx=v[j].x-mean, dy=v[j].y-mean, dz=v[j].z-mean, dw=v[j].w-mean;
    vs += dx*dx + dy*dy + dz*dz + dw*dw;
  }
  #pragma unroll
  for (int o=32;o;o>>=1) vs += __shfl_xor(vs, o);
  float rs = rsqrtf(vs*(1.f/768.f) + 1e-6f);
  bf16* orow = out + (size_t)row*768;
  #pragma unroll
  for (int j=0;j<3;j++){
    int d0 = lane*4 + j*256;
    float4 gv = *(const float4*)(g + d0);
    float4 bv = *(const float4*)(b + d0);
    uint2 pk;
    pk.x = pk2((v[j].x-mean)*rs*gv.x + bv.x, (v[j].y-mean)*rs*gv.y + bv.y);
    pk.y = pk2((v[j].z-mean)*rs*gv.z + bv.z, (v[j].w-mean)*rs*gv.w + bv.w);
    *(uint2*)(orow + d0) = pk;
  }
}

// ---------------- MFMA flash attention (round-3/15 proven: 192 blocks x 4 waves) ----------------
__global__ __launch_bounds__(256) void attn_k(const bf16* __restrict__ qkv, bf16* __restrict__ o){
  __shared__ char Kc[2][32*128];
  __shared__ bf16 Vt[2][64][40];
  __shared__ bf16 Pl[4][32][40];

  const int blk = blockIdx.x;
  const int half = blk & 1, bh = blk >> 1;
  const int b = bh / 12, h = bh % 12;
  const int t = threadIdx.x, wave = t>>6, lane = t&63;
  const int qbase = half*128 + wave*32;
  const bf16* base = qkv + (size_t)b*NTOK*2304 + h*64;

  short8 qf[2][2];
  #pragma unroll
  for (int qt=0;qt<2;qt++){
    int row = qbase + qt*16 + (lane&15); row = row < NTOK ? row : NTOK-1;
    const bf16* qr = base + (size_t)row*2304 + (lane>>4)*8;
    qf[qt][0] = *(const short8*)(qr);
    qf[qt][1] = *(const short8*)(qr + 32);
  }

  f32x4 Oa[2][4];
  float mrow[2][4], srow[2][4];
  #pragma unroll
  for (int i=0;i<2;i++)
    #pragma unroll
    for (int j=0;j<4;j++){ Oa[i][j] = (f32x4){0.f,0.f,0.f,0.f}; mrow[i][j] = -1e30f; srow[i][j] = 0.f; }

  const int sr = t>>3, sc = (t&7)*8;
  auto ldK = [&](int c)->uint4{
    int kv = c*32 + sr; kv = kv < NTOK ? kv : NTOK-1;
    return *(const uint4*)(base + (size_t)kv*2304 + 768 + sc);
  };
  auto ldV = [&](int c)->uint4{
    int kv = c*32 + sr;
    uint4 r = {0,0,0,0};
    if (kv < NTOK) r = *(const uint4*)(base + (size_t)kv*2304 + 1536 + sc);
    return r;
  };
  auto wrK = [&](int buf, uint4 kvv){
    *(uint4*)(Kc[buf] + sr*128 + ((sc*2) ^ ((sr&7)<<4))) = kvv;
  };
  auto wrV = [&](int buf, uint4 vvv){
    union{ uint4 u; short s[8]; } w; w.u = vvv;
    #pragma unroll
    for (int j=0;j<8;j++) *(short*)&Vt[buf][sc+j][sr] = w.s[j];
  };

  { uint4 k0 = ldK(0), v0 = ldV(0); wrK(0,k0); wrV(0,v0); }
  __syncthreads();

  for (int c=0;c<7;c++){
    const int buf = c & 1;
    uint4 kn, vn; const bool pf = (c < 6);
    if (pf){ kn = ldK(c+1); vn = ldV(c+1); }

    f32x4 S[2][2];
    #pragma unroll
    for (int i=0;i<2;i++)
      #pragma unroll
      for (int j=0;j<2;j++) S[i][j] = (f32x4){0.f,0.f,0.f,0.f};
    #pragma unroll
    for (int kt=0;kt<2;kt++){
      int rk = kt*16 + (lane&15);
      const char* kb = Kc[buf] + rk*128;
      int swz = (rk&7)<<4;
      short8 b0 = *(const short8*)(kb + (((lane>>4)*16) ^ swz));
      short8 b1 = *(const short8*)(kb + ((64 + (lane>>4)*16) ^ swz));
      #pragma unroll
      for (int qt=0;qt<2;qt++){
        S[qt][kt] = __builtin_amdgcn_mfma_f32_16x16x32_bf16(qf[qt][0], b0, S[qt][kt],0,0,0);
        S[qt][kt] = __builtin_amdgcn_mfma_f32_16x16x32_bf16(qf[qt][1], b1, S[qt][kt],0,0,0);
      }
    }

    #pragma unroll
    for (int qt=0;qt<2;qt++){
      #pragma unroll
      for (int r=0;r<4;r++){
        float s0 = S[qt][0][r]*0.125f, s1 = S[qt][1][r]*0.125f;
        if (c == 6){
          if (192 + (lane&15) >= NTOK) s0 = -1e30f;
          s1 = -1e30f;
        }
        float mx = fmaxf(s0, s1);
        mx = fmaxf(mx, __shfl_xor(mx,1));
        mx = fmaxf(mx, __shfl_xor(mx,2));
        mx = fmaxf(mx, __shfl_xor(mx,4));
        mx = fmaxf(mx, __shfl_xor(mx,8));
        float mo = mrow[qt][r];
        float mn = fmaxf(mo, mx);
        float scl = __expf(mo - mn);
        mrow[qt][r] = mn;
        float p0 = __expf(s0 - mn), p1 = __expf(s1 - mn);
        srow[qt][r] = srow[qt][r]*scl + p0 + p1;
        #pragma unroll
        for (int dt=0;dt<4;dt++) Oa[qt][dt][r] *= scl;
        int pr = qt*16 + (lane>>4)*4 + r;
        Pl[wave][pr][lane&15]      = f2bf(p0);
        Pl[wave][pr][16+(lane&15)] = f2bf(p1);
      }
    }

    short8 vb[4];
    #pragma unroll
    for (int dt=0;dt<4;dt++)
      vb[dt] = *(const short8*)(&Vt[buf][dt*16+(lane&15)][(lane>>4)*8]);
    #pragma unroll
    for (int qt=0;qt<2;qt++){
      short8 pa = *(const short8*)(&Pl[wave][qt*16+(lane&15)][(lane>>4)*8]);
      #pragma unroll
      for (int dt=0;dt<4;dt++)
        Oa[qt][dt] = __builtin_amdgcn_mfma_f32_16x16x32_bf16(pa, vb[dt], Oa[qt][dt],0,0,0);
    }

    if (pf){ wrK(buf^1, kn); wrV(buf^1, vn); }
    __syncthreads();
  }

  #pragma unroll
  for (int qt=0;qt<2;qt++)
    #pragma unroll
    for (int r=0;r<4;r++){
      float s = srow[qt][r];
      s += __shfl_xor(s,1); s += __shfl_xor(s,2);
      s += __shfl_xor(s,4); s += __shfl_xor(s,8);
      srow[qt][r] = 1.f/s;
    }
  #pragma unroll
  for (int qt=0;qt<2;qt++){
    #pragma unroll
    for (int r=0;r<4;r++){
      int tok = qbase + qt*16 + (lane>>4)*4 + r;
      if (tok < NTOK){
        bf16* orow = o + ((size_t)(b*NTOK+tok))*768 + h*64 + (lane&15);
        float inv = srow[qt][r];
        #pragma unroll
        for (int dt=0;dt<4;dt++) orow[dt*16] = f2bf(Oa[qt][dt][r]*inv);
      }
    }
  }
}

// ---------------- mean-pool (4-way ILP over rows) ----------------
__global__ void pool_k(const float* __restrict__ x, float* __restrict__ pooled){
  int idx = blockIdx.x*256 + threadIdx.x;
  if (idx >= 8*768) return;
  int b = idx / 768, d = idx % 768;
  const float* col = x + (size_t)(b*NTOK)*768 + d;
  float s0=0.f, s1=0.f, s2=0.f, s3=0.f;
  for (int i=1; i<=196; i+=4){
    s0 += col[(size_t)i*768];
    s1 += col[(size_t)(i+1)*768];
    s2 += col[(size_t)(i+2)*768];
    s3 += col[(size_t)(i+3)*768];
  }
  pooled[idx] = (s0+s1+s2+s3) * (1.f/196.f);
}

// ==================================================================
// Unified bf16 GEMM via global_load_lds (round-9 proven config, FROZEN)
// ==================================================================
template<int BM, int BN, int OUTMODE, int ACT, int FOLD>
__global__ __launch_bounds__(256) void gemm_k(
    const bf16* __restrict__ A, const bf16* __restrict__ W,
    const float* __restrict__ bias, const float* __restrict__ gvec,
    void* __restrict__ Cout,
    int M, int N, int Kst, int kiters, size_t kslab)
{
  constexpr int WCM = BM/2;
  constexpr int WCN = BN/2;
  constexpr int FM  = WCM/16;
  constexpr int FN  = WCN/16;
  constexpr int NW  = BN/32;
  constexpr int LCNT = 1 + NW;

  __shared__ char As[2][BM*128];
  __shared__ char Bs[2][BN*128];

  int mt, nt;
  {
    int gmy = gridDim.y;
    int nwg = gridDim.x * gmy;
    int bid = blockIdx.y * gridDim.x + blockIdx.x;
    int q8 = nwg >> 3, r8 = nwg & 7, xcd = bid & 7, idx = bid >> 3;
    int swz = (xcd < r8 ? xcd*(q8+1) : r8*(q8+1) + (xcd-r8)*q8) + idx;
    nt = swz / gmy; mt = swz - nt*gmy;
  }
  if (FOLD){
    A += (size_t)blockIdx.z * (size_t)M * 64;
    W += (size_t)blockIdx.z * (size_t)N * 64;
  }
  const int kz = FOLD ? 0 : blockIdx.z;
  const int k0 = kz * kiters;
  const int t = threadIdx.x, wave = t>>6, lane = t&63;
  const int wr = wave>>1, wc = wave&1;
  const int KT = kiters;

  const int srow = t >> 3;
  const int swzc = ((t&7)<<4) ^ ((srow&7)<<4);

  f32x4 acc[FM][FN];
  #pragma unroll
  for (int i=0;i<FM;i++)
    #pragma unroll
    for (int j=0;j<FN;j++) acc[i][j] = (f32x4){0.f,0.f,0.f,0.f};

  auto STAGE = [&](int it, int buf){
    {
      int gm = mt*BM + srow; gm = gm < M ? gm : M-1;
      gload16((const char*)A + (size_t)gm*Kst*2 + (size_t)(k0+it)*128 + swzc,
              As[buf] + wave*1024);
    }
    #pragma unroll
    for (int c=0;c<NW;c++){
      int gn = nt*BN + 32*c + srow;
      gload16((const char*)W + (size_t)gn*Kst*2 + (size_t)(k0+it)*128 + swzc,
              Bs[buf] + c*4096 + wave*1024);
    }
  };

  const int lrow = lane & 15;
  const int lkb  = (lane >> 4) * 16;
  auto computeTile = [&](int buf){
    __builtin_amdgcn_s_setprio(1);
    #pragma unroll
    for (int kk=0; kk<2; kk++){
      short8 af[FM]; short8 bw[FN];
      #pragma unroll
      for (int f=0; f<FM; f++){
        int ra = wr*WCM + f*16 + lrow;
        af[f] = *(const short8*)(As[buf] + ra*128 + ((kk*64 + lkb) ^ ((ra&7)<<4)));
      }
      #pragma unroll
      for (int f=0; f<FN; f++){
        int rb = wc*WCN + f*16 + lrow;
        bw[f] = *(const short8*)(Bs[buf] + rb*128 + ((kk*64 + lkb) ^ ((rb&7)<<4)));
      }
      #pragma unroll
      for (int i=0;i<FM;i++)
        #pragma unroll
        for (int j=0;j<FN;j++)
          acc[i][j] = __builtin_amdgcn_mfma_f32_16x16x32_bf16(af[i], bw[j], acc[i][j], 0, 0, 0);
    }
    __builtin_amdgcn_s_setprio(0);
  };

  STAGE(0, 0);
  if (KT > 1) STAGE(1, 1);

  for (int it = 0; it < KT; ++it){
    if (it == KT-1) wait_vm<0>(); else wait_vm<LCNT>();
    __builtin_amdgcn_s_barrier();
    computeTile(it & 1);
    asm volatile("s_waitcnt lgkmcnt(0)" ::: "memory");
    __builtin_amdgcn_s_barrier();
    if (it+2 < KT) STAGE(it+2, it & 1);
  }

  const int erow = (lane >> 4) * 4, ecol = lane & 15;
  #pragma unroll
  for (int i=0;i<FM;i++){
    #pragma unroll
    for (int j=0;j<FN;j++){
      int n = nt*BN + wc*WCN + j*16 + ecol;
      float bv = (bias != nullptr) ? bias[n] : 0.f;
      float gv = (OUTMODE==2) ? gvec[n] : 0.f;
      #pragma unroll
      for (int q=0; q<4; q++){
        int m = mt*BM + wr*WCM + i*16 + erow + q;
        if (m < M){
          float v = acc[i][j][q] + bv;
          if (ACT == 1) v = gelu_tanh(v);
          if (ACT == 2) v = fmaxf(v, 0.f);
          size_t off = (size_t)m*N + n;
          if (OUTMODE == 0)      ((float*)Cout)[(size_t)kz*kslab + off] = v;
          else if (OUTMODE == 1) ((bf16*)Cout)[off] = f2bf(v);
          else if (OUTMODE == 2) ((float*)Cout)[off] += gv * v;
          else if (OUTMODE == 4){
            int bb = m / 196, rr = m - bb*196;
            ((float*)Cout)[((size_t)(bb*NTOK + rr + 1))*768 + n] = v;
          }
          else {
            bf16* C = (bf16*)Cout + (FOLD ? (size_t)blockIdx.z*(size_t)M*N : (size_t)0);
            C[off] = f2bf(bf2f(C[off]) + v);
          }
        }
      }
    }
  }
}

// ===================================================================
extern "C" void kernel_launch(void* const* d_in, const int* in_sizes, int n_in,
                              void* d_out, int out_size, void* d_ws, size_t ws_size,
                              hipStream_t stream){
  (void)in_sizes; (void)n_in; (void)out_size; (void)ws_size;
  const float* img    = (const float*)d_in[0];
  const float* patchw = (const float*)d_in[1];
  const float* patchb = (const float*)d_in[2];
  const float* cls    = (const float*)d_in[3];
  const float* ln1g   = (const float*)d_in[4];
  const float* ln1b   = (const float*)d_in[5];
  const float* ln2g   = (const float*)d_in[6];
  const float* ln2b   = (const float*)d_in[7];
  const float* g1     = (const float*)d_in[8];
  const float* g2     = (const float*)d_in[9];
  const int*   qkvq   = (const int*)d_in[10];
  const float* qkvs   = (const float*)d_in[11];
  const float* qkvb   = (const float*)d_in[12];
  const float* aQ     = (const float*)d_in[13];
  const float* bQ     = (const float*)d_in[14];
  const int*   projq  = (const int*)d_in[15];
  const float* projs  = (const float*)d_in[16];
  const float* projb  = (const float*)d_in[17];
  const float* aP     = (const float*)d_in[18];
  const float* bP     = (const float*)d_in[19];
  const int*   fc1q   = (const int*)d_in[20];
  const float* fc1s   = (const float*)d_in[21];
  const float* fc1b   = (const float*)d_in[22];
  const int*   fc2q   = (const int*)d_in[23];
  const float* fc2s   = (const float*)d_in[24];
  const float* fc2b   = (const float*)d_in[25];
  const float* fcn_g  = (const float*)d_in[26];
  const float* fcn_b  = (const float*)d_in[27];
  const float* headw  = (const float*)d_in[28];
  const float* headb  = (const float*)d_in[29];
  float* out = (float*)d_out;

  char* wp = (char*)d_ws;
  auto alloc = [&](size_t bytes)->char* {
    char* r = wp; wp += (bytes + 255) & ~(size_t)255; return r;
  };
  float* x      = (float*)alloc((size_t)MTOK*768*4);
  bf16*  qkvo   = (bf16*) alloc((size_t)MTOK*2304*2);
  bf16*  h      = (bf16*) alloc((size_t)MTOK*768*2);
  bf16*  h1     = (bf16*) alloc((size_t)MTOK*3072*2);
  bf16*  ob     = (bf16*) alloc((size_t)MTOK*768*2);
  bf16*  p      = (bf16*) alloc((size_t)MPATCH*768*2);
  float* pooled = (float*)alloc((size_t)8*768*4);
  bf16*  pooledb= (bf16*) alloc((size_t)8*768*2);
  bf16* wqb = (bf16*)alloc((size_t)12*2304*768*2);
  bf16* wpb = (bf16*)alloc((size_t)12*768*768*2);
  bf16* w1b = (bf16*)alloc((size_t)12*3072*768*2);
  bf16* w2b = (bf16*)alloc((size_t)12*768*3072*2);
  bf16* patchwb = (bf16*)alloc((size_t)768*768*2);
  bf16* headwb  = (bf16*)alloc((size_t)512*768*2);
  bf16* bQs = (bf16*)alloc((size_t)12*2304*64*2);
  bf16* bPs = (bf16*)alloc((size_t)12*768*64*2);
  bf16* aQT = (bf16*)alloc((size_t)12*768*64*2);
  bf16* aPT = (bf16*)alloc((size_t)12*768*64*2);

  const int GM32 = (MTOK + 31) / 32;   // 50

  // ---- one-time weight prep: dequant (6 chunks), convert, transpose, LoRA fold ----
  dq_k<768><<<2048, 256, 0, stream>>>(qkvq, qkvs, wqb, 12*2304*768/16);
  dq_k<768><<<2048, 256, 0, stream>>>(projq, projs, wpb, 12*768*768/16);
  dq_k<768><<<2048, 256, 0, stream>>>(fc1q, fc1s, w1b, 6*3072*768/16);
  dq_k<768><<<2048, 256, 0, stream>>>(fc1q + (size_t)6*3072*768, fc1s + (size_t)6*3072*12,
                                      w1b + (size_t)6*3072*768, 6*3072*768/16);
  dq_k<3072><<<2048, 256, 0, stream>>>(fc2q, fc2s, w2b, 6*768*3072/16);
  dq_k<3072><<<2048, 256, 0, stream>>>(fc2q + (size_t)6*768*3072, fc2s + (size_t)6*768*48,
                                       w2b + (size_t)6*768*3072, 6*768*3072/16);
  cvtall_k<<<1024, 256, 0, stream>>>(patchw, patchwb, headw, headwb, bQ, bQs, bP, bPs);
  transall_k<<<dim3(12, 12, 2), 256, 0, stream>>>(aQ, aQT, aP, aPT);
  gemm_k<32,64,3,0,1><<<dim3(768/64, 2304/32, 12), 256, 0, stream>>>(
      bQs, aQT, nullptr, nullptr, wqb, 2304, 768, 64, 1, 0);
  gemm_k<32,64,3,0,1><<<dim3(768/64, 768/32, 12), 256, 0, stream>>>(
      bPs, aPT, nullptr, nullptr, wpb, 768, 768, 64, 1, 0);

  patchify_k<<<(MPATCH*768 + 255)/256, 256, 0, stream>>>(img, p);
  // patch embed GEMM scatters directly into x rows [b*197 + r + 1]
  gemm_k<32,64,4,0,0><<<dim3(768/64, MPATCH/32, 1), 256, 0, stream>>>(
      p, patchwb, patchb, nullptr, x, MPATCH, 768, 768, 12, 0);
  cls_k<<<(8*768 + 255)/256, 256, 0, stream>>>(cls, x);

  for (int l=0; l<12; l++){
    const bf16* wq_l = wqb + (size_t)l*2304*768;
    const bf16* wp_l = wpb + (size_t)l*768*768;
    const bf16* w1_l = w1b + (size_t)l*3072*768;
    const bf16* w2_l = w2b + (size_t)l*768*3072;

    ln_k<<<(MTOK+3)/4, 256, 0, stream>>>(x, ln1g + l*768, ln1b + l*768, h, MTOK);
    gemm_k<32,128,1,0,0><<<dim3(2304/128, GM32, 1), 256, 0, stream>>>(
        h, wq_l, qkvb + (size_t)l*2304, nullptr, qkvo, MTOK, 2304, 768, 12, 0);
    attn_k<<<192, 256, 0, stream>>>(qkvo, ob);
    gemm_k<32,64,2,0,0><<<dim3(768/64, GM32, 1), 256, 0, stream>>>(
        ob, wp_l, projb + (size_t)l*768, g1 + l*768, x, MTOK, 768, 768, 12, 0);

    ln_k<<<(MTOK+3)/4, 256, 0, stream>>>(x, ln2g + l*768, ln2b + l*768, h, MTOK);
    gemm_k<32,128,1,1,0><<<dim3(3072/128, GM32, 1), 256, 0, stream>>>(
        h, w1_l, fc1b + (size_t)l*3072, nullptr, h1, MTOK, 3072, 768, 12, 0);
    gemm_k<32,64,2,0,0><<<dim3(768/64, GM32, 1), 256, 0, stream>>>(
        h1, w2_l, fc2b + (size_t)l*768, g2 + l*768, x, MTOK, 768, 3072, 48, 0);
  }

  pool_k<<<(8*768 + 255)/256, 256, 0, stream>>>(x, pooled);
  ln_k<<<2, 256, 0, stream>>>(pooled, fcn_g, fcn_b, pooledb, 8);
  gemm_k<32,128,0,2,0><<<dim3(512/128, 1, 1), 256, 0, stream>>>(
      pooledb, headwb, headb, nullptr, out, 8, 512, 768, 12, 0);
}